// Round 2
// 226.031 us; speedup vs baseline: 1.0026x; 1.0026x over previous
//
#include <hip/hip_runtime.h>
#include <math.h>

// Elementwise B-spline (KAN-style) activation:
//   out = bw * silu(x) + sw * lerp over 3-knot grid
// v5b (re-run of v5 after infra failure; logic identical, builtins guarded):
//  - 4x float4 per thread, block-strided (coalesced, 4 loads in flight -> MLP)
//  - branchless spline: on u = clamp(x,-1,1),
//      y = s1 + d0*min(u,0) + d1*max(u,0)   (exact piecewise-linear identity)
//    replacing floor/cvt/cndmask chains; s1,d0,d1 pre-scaled by sw.
//  - fast reciprocal for sigmoid denominator
//  - nontemporal load/store (pure streaming, no reuse)

typedef float f32x4 __attribute__((ext_vector_type(4)));

#define TPB 256
#define VPT 4   // float4 per thread

__device__ __forceinline__ float fast_rcp(float a) {
#if defined(__has_builtin)
#if __has_builtin(__builtin_amdgcn_rcpf)
    return __builtin_amdgcn_rcpf(a);
#else
    return 1.0f / a;
#endif
#else
    return 1.0f / a;
#endif
}

__global__ __launch_bounds__(TPB) void bspline_act_v5(
    const f32x4* __restrict__ x4,
    const float* __restrict__ cp,    // [5]
    const float* __restrict__ bw_p,  // [1]
    const float* __restrict__ sw_p,  // [1]
    const float* __restrict__ bv,    // [3][5] row-major
    f32x4*       __restrict__ out4,
    int n4)
{
    // Wave-uniform scalar precompute (amortized over 16 elements/thread).
    const float c0 = cp[0], c1 = cp[1], c2 = cp[2], c3 = cp[3], c4 = cp[4];
    const float s0 = bv[0]*c0  + bv[1]*c1  + bv[2]*c2  + bv[3]*c3  + bv[4]*c4;
    const float s1 = bv[5]*c0  + bv[6]*c1  + bv[7]*c2  + bv[8]*c3  + bv[9]*c4;
    const float s2 = bv[10]*c0 + bv[11]*c1 + bv[12]*c2 + bv[13]*c3 + bv[14]*c4;
    const float bw = bw_p[0], sw = sw_p[0];
    const float S1 = sw * s1;          // sw * value at center knot
    const float D0 = sw * (s1 - s0);   // sw * left slope
    const float D1 = sw * (s2 - s1);   // sw * right slope

    const int base = blockIdx.x * (TPB * VPT) + threadIdx.x;

    // Issue all loads first: up to 4 outstanding VMEM ops per thread.
    f32x4 v[VPT];
#pragma unroll
    for (int k = 0; k < VPT; ++k) {
        const int idx = base + k * TPB;
        if (idx < n4) {
            v[k] = __builtin_nontemporal_load(&x4[idx]);
        } else {
            f32x4 z = {0.f, 0.f, 0.f, 0.f};
            v[k] = z;
        }
    }

#pragma unroll
    for (int k = 0; k < VPT; ++k) {
        const int idx = base + k * TPB;
        f32x4 xv = v[k];
        f32x4 r;
#pragma unroll
        for (int e = 0; e < 4; ++e) {
            float x  = xv[e];
            float u  = fminf(fmaxf(x, -1.0f), 1.0f);           // v_med3_f32
            // piecewise-linear: u<0 -> s1 + d0*u ; u>=0 -> s1 + d1*u  (sw-scaled)
            float ys = fmaf(D0, fminf(u, 0.0f),
                       fmaf(D1, fmaxf(u, 0.0f), S1));
            float ex  = __expf(-x);                             // v_mul + v_exp
            float sig = fast_rcp(1.0f + ex);                    // v_add + v_rcp
            r[e] = fmaf(bw * x, sig, ys);
        }
        if (idx < n4) __builtin_nontemporal_store(r, &out4[idx]);
    }
}

// Scalar tail (n % 4 != 0 — not hit for 8*2048*2048, kept for generality).
__global__ void bspline_act_tail(
    const float* __restrict__ x,
    const float* __restrict__ cp,
    const float* __restrict__ bw_p,
    const float* __restrict__ sw_p,
    const float* __restrict__ bv,
    float*       __restrict__ out,
    int start, int n)
{
    int i = start + blockIdx.x * blockDim.x + threadIdx.x;
    if (i >= n) return;
    const float c0 = cp[0], c1 = cp[1], c2 = cp[2], c3 = cp[3], c4 = cp[4];
    const float s0 = bv[0]*c0  + bv[1]*c1  + bv[2]*c2  + bv[3]*c3  + bv[4]*c4;
    const float s1 = bv[5]*c0  + bv[6]*c1  + bv[7]*c2  + bv[8]*c3  + bv[9]*c4;
    const float s2 = bv[10]*c0 + bv[11]*c1 + bv[12]*c2 + bv[13]*c3 + bv[14]*c4;
    const float bw = bw_p[0], sw = sw_p[0];
    const float S1 = sw * s1;
    const float D0 = sw * (s1 - s0);
    const float D1 = sw * (s2 - s1);

    float xv = x[i];
    float u  = fminf(fmaxf(xv, -1.0f), 1.0f);
    float ys = fmaf(D0, fminf(u, 0.0f), fmaf(D1, fmaxf(u, 0.0f), S1));
    float ex  = __expf(-xv);
    float sig = fast_rcp(1.0f + ex);
    out[i] = fmaf(bw * xv, sig, ys);
}

extern "C" void kernel_launch(void* const* d_in, const int* in_sizes, int n_in,
                              void* d_out, int out_size, void* d_ws, size_t ws_size,
                              hipStream_t stream) {
    const float* x  = (const float*)d_in[0];
    const float* cp = (const float*)d_in[1];
    const float* bw = (const float*)d_in[2];
    const float* sw = (const float*)d_in[3];
    const float* bv = (const float*)d_in[4];
    float* out = (float*)d_out;

    const int n  = in_sizes[0];
    const int n4 = n / 4;
    const int rem_start = n4 * 4;

    if (n4 > 0) {
        const int per_block = TPB * VPT;           // 1024 float4 per block
        const int grid = (n4 + per_block - 1) / per_block;
        bspline_act_v5<<<grid, TPB, 0, stream>>>(
            (const f32x4*)x, cp, bw, sw, bv, (f32x4*)out, n4);
    }
    if (rem_start < n) {
        const int rem = n - rem_start;
        bspline_act_tail<<<(rem + 255) / 256, 256, 0, stream>>>(
            x, cp, bw, sw, bv, out, rem_start, n);
    }
}